// Round 19
// baseline (598.349 us; speedup 1.0000x reference)
//
#include <hip/hip_runtime.h>
#include <hip/hip_bf16.h>

// Swin block fused: C=180, NH=6, HD=30, WS=8, SS=4, N=64, B=16, H=W=128.
// R19 = R16 structure + A-fragment register holds (LDS-op diet). At
// launch_bounds(768,3) the register budget (~170) is free since LDS caps us
// at 1 WG/CU; holds cut ~40% of ds_read traffic on the shared LDS pipe.
typedef short s16x8 __attribute__((ext_vector_type(8)));
typedef short s16x4 __attribute__((ext_vector_type(4)));
typedef float f32x4 __attribute__((ext_vector_type(4)));

__device__ __forceinline__ short f2bf(float f) {
    __bf16 h = (__bf16)f;
    return __builtin_bit_cast(short, h);
}
__device__ __forceinline__ float bf2f(short s) {
    return __builtin_bit_cast(float, ((unsigned int)(unsigned short)s) << 16);
}
__device__ __forceinline__ unsigned int pk2(float a, float b) {
    return (unsigned int)(unsigned short)f2bf(a) | ((unsigned int)(unsigned short)f2bf(b) << 16);
}
__device__ __forceinline__ f32x4 mfma16(s16x8 a, s16x8 b, f32x4 c) {
    return __builtin_amdgcn_mfma_f32_16x16x32_bf16(a, b, c, 0, 0, 0);
}
// two ds_read_b64 (8B-aligned rows); conflict-free strides (R15: 10x fewer conflicts)
__device__ __forceinline__ s16x8 ld_b64x2(const short* p) {
    union { s16x8 v; s16x4 h[2]; } u;
    u.h[0] = *(const s16x4*)p;
    u.h[1] = *(const s16x4*)(p + 4);
    return u.v;
}
__device__ __forceinline__ s16x4 pack4(f32x4 a) {
    s16x4 w;
    w[0] = f2bf(a[0]); w[1] = f2bf(a[1]); w[2] = f2bf(a[2]); w[3] = f2bf(a[3]);
    return w;
}

#define SCALE_Q 0.18257418583505536f
#define ONE_BF16 ((short)0x3F80)
// LDS strides in shorts; dword-stride mod 32 has gcd 2 -> ~2-way max on b64 reads.
#define RA 204
#define PS 76
#define HS 196

// ---------------- workspace layout (bytes) ----------------
// Whead bf16 [6][96][192] @ 0       rows: 0-31 q(scaled), 32-63 k, 64-95 v; col180=bias
// Wproj bf16 [192][192]   @ 221184  col180=bias
// Wfc1  bf16 [384][192]   @ 294912  col180=bias
// Wfc2  bf16 [192][384]   @ 442368
// battn bf16 [6][64(n)][64(m)] @ 589824  (n = q-token major)   total 638976

__global__ void k_prep(const float* __restrict__ qkv_w, const float* __restrict__ qkv_b,
                       const float* __restrict__ proj_w, const float* __restrict__ proj_b,
                       const float* __restrict__ fc1_w, const float* __restrict__ fc1_b,
                       const float* __restrict__ fc2_w,
                       const float* __restrict__ rpb,
                       short* __restrict__ Whead, short* __restrict__ Wproj,
                       short* __restrict__ Wfc1, short* __restrict__ Wfc2,
                       short* __restrict__ battn) {
    int gt = blockIdx.x * 256 + threadIdx.x;
    int stride = gridDim.x * 256;
    for (int idx = gt; idx < 6 * 96 * 192; idx += stride) {
        int h = idx / (96 * 192), rem = idx - h * 96 * 192;
        int rr = rem / 192, kk = rem - rr * 192;
        int seg = rr >> 5, hd = rr & 31;
        float val = 0.f;
        if (hd < 30) {
            int ch = seg * 180 + h * 30 + hd;
            if (kk < 180) val = qkv_w[ch * 180 + kk];
            else if (kk == 180) val = qkv_b[ch];
            if (seg == 0) val *= SCALE_Q;
        }
        Whead[idx] = f2bf(val);
    }
    for (int idx = gt; idx < 192 * 192; idx += stride) {
        int rr = idx / 192, kk = idx - rr * 192;
        float val = 0.f;
        if (rr < 180) {
            if (kk < 180) val = proj_w[rr * 180 + kk];
            else if (kk == 180) val = proj_b[rr];
        }
        Wproj[idx] = f2bf(val);
    }
    for (int idx = gt; idx < 384 * 192; idx += stride) {
        int rr = idx / 192, kk = idx - rr * 192;
        float val = 0.f;
        if (rr < 360) {
            if (kk < 180) val = fc1_w[rr * 180 + kk];
            else if (kk == 180) val = fc1_b[rr];
        }
        Wfc1[idx] = f2bf(val);
    }
    for (int idx = gt; idx < 192 * 384; idx += stride) {
        int rr = idx / 384, kk = idx - rr * 384;
        Wfc2[idx] = (rr < 180 && kk < 360) ? f2bf(fc2_w[rr * 360 + kk]) : (short)0;
    }
    // battn[h][n][m] (n = q-token major)
    for (int idx = gt; idx < 6 * 64 * 64; idx += stride) {
        int h = idx >> 12, n = (idx >> 6) & 63, m = idx & 63;
        int r1 = n >> 3, c1 = n & 7, r2 = m >> 3, c2 = m & 7;
        int ridx = (r1 - r2 + 7) * 15 + (c1 - c2 + 7);
        battn[idx] = f2bf(rpb[ridx * 6 + h]);
    }
}

// ---------------- fully fused kernel: TWO windows per block ----------------
// 768 thr = 12 waves = 2 windows x 6 head-waves -> balanced 3 waves/SIMD.
// Per-half layout (80384 B; total 160768 <= 163840):
//  regionA @0     (26112): xln[64][RA] -> xout -> ylds -> mo  (pad col180=1.0)
//  regP @26112    (29184): patches 6x4864 (stride PS) -> pout/y bf16 [64][RA]
//  hid  @55296    (25088): bf16 [64][HS] per-K-half fc1 output
__global__ __launch_bounds__(768, 3)
void k_fused(const float* __restrict__ x, const float* __restrict__ g1, const float* __restrict__ b1,
             const short* __restrict__ Whead,
             const short* __restrict__ Wproj,
             const short* __restrict__ battn,
             const float* __restrict__ g2, const float* __restrict__ b2,
             const short* __restrict__ Wfc1,
             const short* __restrict__ Wfc2, const float* __restrict__ fb2,
             float* __restrict__ out) {
    __shared__ __align__(16) char smem[160768];

    const int tid = threadIdx.x;
    const int wvg = tid >> 6;                 // 0..11
    const int half = (wvg >= 6) ? 1 : 0;      // which window
    const int wv = wvg - half * 6;            // local head-wave 0..5
    const int l = tid & 63, l15 = l & 15, lg = l >> 4;
    const int tl = tid - half * 384;          // local tid 0..383

    char* sm = smem + half * 80384;
    short* xln  = (short*)sm;                 // [64][RA]
    short* xout = (short*)sm;                 // overlays
    short* ylds = (short*)sm;                 // overlays
    short* mo   = (short*)sm;                 // overlays (after fc1 reads done)
    short* regP = (short*)(sm + 26112);
    short* pout = regP;                       // bf16 [64][RA] -> becomes y in place
    short* ybuf = regP;
    short* hid  = (short*)(sm + 55296);       // bf16 [64][HS]
    short* patch = regP + wv * 2432;          // 4864 B each

    const int wid = blockIdx.x * 2 + half;
    const int b = wid >> 8, win = wid & 255, wi = win >> 4, wj = win & 15;
    const bool edge = (wi == 15) || (wj == 15);
    const f32x4 vzero = {0.f, 0.f, 0.f, 0.f};

    const int t = tl >> 2, sub = tl & 3;
    size_t rowbase = 0;
    if (tl < 256) {
        const int r = t >> 3, c = t & 7;
        const int gi = (wi * 8 + r + 4) & 127, gj = (wj * 8 + c + 4) & 127;
        rowbase = ((size_t)b * 16384 + (size_t)gi * 128 + gj) * 180;
    }
    const float* xrow = x + rowbase;
    float* yrow = out + rowbase;

    // x held in f32 regs from P1 through P4 (48 VGPRs; budget ~170 at 1 WG/CU)
    float4 xr[12];

    // ---- P1: LN1 -> xln ----
    if (tl < 256) {
        float s1 = 0.f, s2 = 0.f;
#pragma unroll
        for (int m = 0; m < 12; ++m) {
            int jj = sub + 4 * m;
            if (jj < 45) {
                float4 t4 = *(const float4*)&xrow[4 * jj];
                xr[m] = t4;
                s1 += t4.x + t4.y + t4.z + t4.w;
                s2 += t4.x * t4.x + t4.y * t4.y + t4.z * t4.z + t4.w * t4.w;
            }
        }
        s1 += __shfl_xor(s1, 1); s2 += __shfl_xor(s2, 1);
        s1 += __shfl_xor(s1, 2); s2 += __shfl_xor(s2, 2);
        const float mu = s1 * (1.f / 180.f);
        const float rstd = rsqrtf(s2 * (1.f / 180.f) - mu * mu + 1e-5f);
#pragma unroll
        for (int m = 0; m < 12; ++m) {
            int jj = sub + 4 * m;
            if (jj < 45) {
                float4 g4 = *(const float4*)&g1[4 * jj];
                float4 b4 = *(const float4*)&b1[4 * jj];
                s16x4 w;
                w[0] = f2bf((xr[m].x - mu) * rstd * g4.x + b4.x);
                w[1] = f2bf((xr[m].y - mu) * rstd * g4.y + b4.y);
                w[2] = f2bf((xr[m].z - mu) * rstd * g4.z + b4.z);
                w[3] = f2bf((xr[m].w - mu) * rstd * g4.w + b4.w);
                *(s16x4*)&xln[t * RA + 4 * jj] = w;
            }
        }
    } else {
        for (int k = tl - 256; k < 64 * 12; k += 128) {
            int rr = k / 12, cc = k - rr * 12;
            xln[rr * RA + 180 + cc] = (cc == 0) ? ONE_BF16 : (short)0;
        }
    }
    __syncthreads();   // B1: xln ready (both halves)

    // ---- P2: per-wave head staging; A-fragments held in regs (1 read, 3 uses) ----
    const short* Wh = Whead + wv * (96 * 192);
    s16x8 qf[4], kf[4], vf[2][2];
    {
        s16x8 af[4][6];
#pragma unroll
        for (int i = 0; i < 4; ++i)
#pragma unroll
            for (int ks = 0; ks < 6; ++ks)
                af[i][ks] = ld_b64x2(&xln[(i * 16 + l15) * RA + ks * 32 + lg * 8]);

        // Q (swapped: D row=ch, col=token) -> patch [64][36]
#pragma unroll
        for (int jl = 0; jl < 2; ++jl) {
            f32x4 acc[4] = {vzero, vzero, vzero, vzero};
#pragma unroll
            for (int ks = 0; ks < 6; ++ks) {
                s16x8 bwk = *(const s16x8*)&Wh[(jl * 16 + l15) * 192 + ks * 32 + lg * 8];
#pragma unroll
                for (int i = 0; i < 4; ++i) acc[i] = mfma16(bwk, af[i][ks], acc[i]);
            }
#pragma unroll
            for (int i = 0; i < 4; ++i)
                *(s16x4*)&patch[(i * 16 + l15) * 36 + jl * 16 + lg * 4] = pack4(acc[i]);
        }
#pragma unroll
        for (int i = 0; i < 4; ++i) qf[i] = ld_b64x2(&patch[(i * 16 + l15) * 36 + lg * 8]);

        // K (swapped) -> patch [64][36] (reuse)
#pragma unroll
        for (int jl = 0; jl < 2; ++jl) {
            f32x4 acc[4] = {vzero, vzero, vzero, vzero};
#pragma unroll
            for (int ks = 0; ks < 6; ++ks) {
                s16x8 bwk = *(const s16x8*)&Wh[(32 + jl * 16 + l15) * 192 + ks * 32 + lg * 8];
#pragma unroll
                for (int i = 0; i < 4; ++i) acc[i] = mfma16(bwk, af[i][ks], acc[i]);
            }
#pragma unroll
            for (int i = 0; i < 4; ++i)
                *(s16x4*)&patch[(i * 16 + l15) * 36 + jl * 16 + lg * 4] = pack4(acc[i]);
        }
#pragma unroll
        for (int j = 0; j < 4; ++j) kf[j] = ld_b64x2(&patch[(j * 16 + l15) * 36 + lg * 8]);

        // V (unswapped: D col=hd, rows=token) -> VhT [32][PS]
#pragma unroll
        for (int jl = 0; jl < 2; ++jl) {
            f32x4 acc[4] = {vzero, vzero, vzero, vzero};
#pragma unroll
            for (int ks = 0; ks < 6; ++ks) {
                s16x8 bwk = *(const s16x8*)&Wh[(64 + jl * 16 + l15) * 192 + ks * 32 + lg * 8];
#pragma unroll
                for (int i = 0; i < 4; ++i) acc[i] = mfma16(af[i][ks], bwk, acc[i]);
            }
#pragma unroll
            for (int i = 0; i < 4; ++i)
                *(s16x4*)&patch[(jl * 16 + l15) * PS + i * 16 + lg * 4] = pack4(acc[i]);
        }
#pragma unroll
        for (int j2 = 0; j2 < 2; ++j2)
#pragma unroll
            for (int ksv = 0; ksv < 2; ++ksv)
                vf[j2][ksv] = ld_b64x2(&patch[(j2 * 16 + l15) * PS + ksv * 32 + lg * 8]);
    }   // af released

    __syncthreads();   // Bx: all xln reads done -> region A reusable as xout

    // ---- attention: S^T = mfma(kf,qf); per-lane softmax; PV^T = mfma(vf,pa) ----
    {
        const short* bb = battn + wv * 4096;
#pragma unroll
        for (int i = 0; i < 4; ++i) {
            const int n = i * 16 + l15;            // q-token (lane col)
            f32x4 sc[4];
#pragma unroll
            for (int j = 0; j < 4; ++j) sc[j] = mfma16(kf[j], qf[i], vzero);
            int cnt_n = 0;
            if (edge) {
                int rn = n >> 3, cn = n & 7;
                cnt_n = (wi == 15 ? ((rn >= 4) ? 2 : 1) : 0) * 3 + (wj == 15 ? ((cn >= 4) ? 2 : 1) : 0);
            }
            float p[4][4];
#pragma unroll
            for (int j = 0; j < 4; ++j) {
                s16x4 bv = *(const s16x4*)&bb[n * 64 + j * 16 + lg * 4];
#pragma unroll
                for (int tt = 0; tt < 4; ++tt) {
                    float s = sc[j][tt] + bf2f(bv[tt]);
                    if (edge) {
                        int m = j * 16 + lg * 4 + tt;
                        int rm = m >> 3, cm = m & 7;
                        int cnt_m = (wi == 15 ? ((rm >= 4) ? 2 : 1) : 0) * 3 + (wj == 15 ? ((cm >= 4) ? 2 : 1) : 0);
                        if (cnt_m != cnt_n) s -= 100.f;
                    }
                    p[j][tt] = s;
                }
            }
            float m0 = p[0][0];
#pragma unroll
            for (int j = 0; j < 4; ++j)
#pragma unroll
                for (int tt = 0; tt < 4; ++tt) m0 = fmaxf(m0, p[j][tt]);
            m0 = fmaxf(m0, __shfl_xor(m0, 16));
            m0 = fmaxf(m0, __shfl_xor(m0, 32));
            float s0 = 0.f;
#pragma unroll
            for (int j = 0; j < 4; ++j)
#pragma unroll
                for (int tt = 0; tt < 4; ++tt) { float e = __expf(p[j][tt] - m0); p[j][tt] = e; s0 += e; }
            s0 += __shfl_xor(s0, 16);
            s0 += __shfl_xor(s0, 32);
            const float sm0 = __builtin_amdgcn_rcpf(s0);

            short* pb = patch + (i & 1) * 1216;   // [16][PS] ping-pong
#pragma unroll
            for (int j = 0; j < 4; ++j) {
                f32x4 ps;
#pragma unroll
                for (int tt = 0; tt < 4; ++tt) ps[tt] = p[j][tt] * sm0;
                *(s16x4*)&pb[l15 * PS + j * 16 + lg * 4] = pack4(ps);
            }
            s16x8 pa0 = ld_b64x2(&pb[l15 * PS + lg * 8]);
            s16x8 pa1 = ld_b64x2(&pb[l15 * PS + 32 + lg * 8]);
            f32x4 ov0 = mfma16(vf[0][0], pa0, vzero);   // D: row=hd, col=qtok
            ov0 = mfma16(vf[0][1], pa1, ov0);
            f32x4 ov1 = mfma16(vf[1][0], pa0, vzero);
            ov1 = mfma16(vf[1][1], pa1, ov1);
            short* xo = &xout[n * RA + wv * 30];
            unsigned int w0 = pk2(ov0[0], ov0[1]);
            unsigned int w1 = pk2(ov0[2], ov0[3]);
            *(unsigned int*)&xo[lg * 4] = w0;
            *(unsigned int*)&xo[lg * 4 + 2] = w1;
            unsigned int w2 = pk2(ov1[0], ov1[1]);
            if (lg < 3) {
                unsigned int w3 = pk2(ov1[2], ov1[3]);
                *(unsigned int*)&xo[16 + lg * 4] = w2;
                *(unsigned int*)&xo[16 + lg * 4 + 2] = w3;
            } else {
                *(unsigned int*)&xo[28] = w2;   // hd 28,29
            }
        }
    }
    __syncthreads();   // B3: xout complete, patches dead

    // ---- proj (swapped, af2 held) -> pout bf16 [token][ch] ----
    {
        s16x8 af2[4][6];
#pragma unroll
        for (int i = 0; i < 4; ++i)
#pragma unroll
            for (int ks = 0; ks < 6; ++ks)
                af2[i][ks] = ld_b64x2(&xout[(i * 16 + l15) * RA + ks * 32 + lg * 8]);
#pragma unroll
        for (int jl = 0; jl < 2; ++jl) {
            const int cb = wv * 32 + jl * 16 + lg * 4;
            f32x4 acc[4] = {vzero, vzero, vzero, vzero};
#pragma unroll
            for (int ks = 0; ks < 6; ++ks) {
                s16x8 bwk = *(const s16x8*)&Wproj[(wv * 32 + jl * 16 + l15) * 192 + ks * 32 + lg * 8];
#pragma unroll
                for (int i = 0; i < 4; ++i) acc[i] = mfma16(bwk, af2[i][ks], acc[i]);
            }
            if (cb <= 176) {
#pragma unroll
                for (int i = 0; i < 4; ++i)
                    *(s16x4*)&pout[(i * 16 + l15) * RA + cb] = pack4(acc[i]);
            }
        }
    }
    __syncthreads();   // B4: pout ready, xout dead

    // ---- P4: y = x(regs) + pout -> IN PLACE bf16 (ybuf == pout); LN2 -> ylds ----
    if (tl < 256) {
        float s1 = 0.f, s2 = 0.f;
        unsigned int pA[12], pB[12];
#pragma unroll
        for (int m = 0; m < 12; ++m) {
            int jj = sub + 4 * m;
            if (jj < 45) {
                s16x4 pv = *(const s16x4*)&pout[t * RA + 4 * jj];
                float4 y4;
                y4.x = xr[m].x + bf2f(pv[0]); y4.y = xr[m].y + bf2f(pv[1]);
                y4.z = xr[m].z + bf2f(pv[2]); y4.w = xr[m].w + bf2f(pv[3]);
                pA[m] = pk2(y4.x, y4.y);
                pB[m] = pk2(y4.z, y4.w);
                *(unsigned int*)&ybuf[t * RA + 4 * jj] = pA[m];
                *(unsigned int*)&ybuf[t * RA + 4 * jj + 2] = pB[m];
                s1 += y4.x + y4.y + y4.z + y4.w;
                s2 += y4.x * y4.x + y4.y * y4.y + y4.z * y4.z + y4.w * y4.w;
            }
        }
        s1 += __shfl_xor(s1, 1); s2 += __shfl_xor(s2, 1);
        s1 += __shfl_xor(s1, 2); s2 += __shfl_xor(s2, 2);
        const float mu = s1 * (1.f / 180.f);
        const float rstd = rsqrtf(s2 * (1.f / 180.f) - mu * mu + 1e-5f);
#pragma unroll
        for (int m = 0; m < 12; ++m) {
            int jj = sub + 4 * m;
            if (jj < 45) {
                float4 g4 = *(const float4*)&g2[4 * jj];
                float4 b4 = *(const float4*)&b2[4 * jj];
                float ylo0 = bf2f((short)(pA[m] & 0xFFFFu));
                float yhi0 = bf2f((short)(pA[m] >> 16));
                float ylo1 = bf2f((short)(pB[m] & 0xFFFFu));
                float yhi1 = bf2f((short)(pB[m] >> 16));
                s16x4 w;
                w[0] = f2bf((ylo0 - mu) * rstd * g4.x + b4.x);
                w[1] = f2bf((yhi0 - mu) * rstd * g4.y + b4.y);
                w[2] = f2bf((ylo1 - mu) * rstd * g4.z + b4.z);
                w[3] = f2bf((yhi1 - mu) * rstd * g4.w + b4.w);
                *(s16x4*)&ylds[t * RA + 4 * jj] = w;
            }
        }
    } else {
        for (int k = tl - 256; k < 64 * 12; k += 128) {
            int rr = k / 12, cc = k - rr * 12;
            ylds[rr * RA + 180 + cc] = (cc == 0) ? ONE_BF16 : (short)0;
        }
    }
    __syncthreads();   // B5: ylds + y(bf16, in place) ready

    // ---- MLP in 2 K-halves of 192: fc1 (ay held, 2 tiles/wave) -> hid -> fc2 ----
    f32x4 acc3[2][4];
#pragma unroll
    for (int jl = 0; jl < 2; ++jl)
#pragma unroll
        for (int i = 0; i < 4; ++i) acc3[jl][i] = vzero;

#pragma unroll
    for (int kh = 0; kh < 2; ++kh) {
        // fc1: wave's out tiles j = kh*12 + wv*2 + jl; GELU; packed store
        {
            s16x8 ay[4][6];
#pragma unroll
            for (int i = 0; i < 4; ++i)
#pragma unroll
                for (int ks = 0; ks < 6; ++ks)
                    ay[i][ks] = ld_b64x2(&ylds[(i * 16 + l15) * RA + ks * 32 + lg * 8]);
#pragma unroll
            for (int jl = 0; jl < 2; ++jl) {
                f32x4 acc[4] = {vzero, vzero, vzero, vzero};
#pragma unroll
                for (int ks = 0; ks < 6; ++ks) {
                    s16x8 bwk = *(const s16x8*)&Wfc1[((kh * 12 + wv * 2 + jl) * 16 + l15) * 192 + ks * 32 + lg * 8];
#pragma unroll
                    for (int i = 0; i < 4; ++i) acc[i] = mfma16(bwk, ay[i][ks], acc[i]);
                }
                const int clb = (wv * 2 + jl) * 16 + lg * 4;   // half-local channel base
#pragma unroll
                for (int i = 0; i < 4; ++i) {
                    s16x4 w;
#pragma unroll
                    for (int tt = 0; tt < 4; ++tt) {
                        float v = acc[i][tt];
                        float u = v * (1.f + 0.044715f * v * v);
                        float e = __expf(-1.5957691216f * u);
                        w[tt] = f2bf(v * __builtin_amdgcn_rcpf(1.f + e));
                    }
                    *(s16x4*)&hid[(i * 16 + l15) * HS + clb] = w;
                }
            }
        }
        __syncthreads();   // hid(kh) ready
        // fc2 partial: K = cols [kh*192, kh*192+192) of Wfc2
#pragma unroll
        for (int ks = 0; ks < 6; ++ks) {
            s16x8 a[4];
#pragma unroll
            for (int i = 0; i < 4; ++i)
                a[i] = ld_b64x2(&hid[(i * 16 + l15) * HS + ks * 32 + lg * 8]);
#pragma unroll
            for (int jl = 0; jl < 2; ++jl) {
                s16x8 bw2 = *(const s16x8*)&Wfc2[((wv * 2 + jl) * 16 + l15) * 384 + kh * 192 + ks * 32 + lg * 8];
#pragma unroll
                for (int i = 0; i < 4; ++i) acc3[jl][i] = mfma16(bw2, a[i], acc3[jl][i]);
            }
        }
        __syncthreads();   // hid consumed (next kh overwrites)
    }

    // ---- fc2 out + fb2 -> mo bf16 [token][ch] (regionA; ylds dead) ----
#pragma unroll
    for (int jl = 0; jl < 2; ++jl) {
        const int cb = (wv * 2 + jl) * 16 + lg * 4;
        if (cb <= 176) {
            float4 f4 = *(const float4*)&fb2[cb];
#pragma unroll
            for (int i = 0; i < 4; ++i) {
                f32x4 a2;
                a2[0] = acc3[jl][i][0] + f4.x;
                a2[1] = acc3[jl][i][1] + f4.y;
                a2[2] = acc3[jl][i][2] + f4.z;
                a2[3] = acc3[jl][i][3] + f4.w;
                *(s16x4*)&mo[(i * 16 + l15) * RA + cb] = pack4(a2);
            }
        }
    }
    __syncthreads();   // B7: mo ready

    // ---- final: out = y(bf16 LDS) + mo, single coalesced write pass ----
    if (tl < 256) {
#pragma unroll
        for (int m = 0; m < 12; ++m) {
            int jj = sub + 4 * m;
            if (jj < 45) {
                s16x4 yv4 = *(const s16x4*)&ybuf[t * RA + 4 * jj];
                s16x4 mv = *(const s16x4*)&mo[t * RA + 4 * jj];
                float4 o;
                o.x = bf2f(yv4[0]) + bf2f(mv[0]);
                o.y = bf2f(yv4[1]) + bf2f(mv[1]);
                o.z = bf2f(yv4[2]) + bf2f(mv[2]);
                o.w = bf2f(yv4[3]) + bf2f(mv[3]);
                *(float4*)&yrow[4 * jj] = o;
            }
        }
    }
}

extern "C" void kernel_launch(void* const* d_in, const int* in_sizes, int n_in,
                              void* d_out, int out_size, void* d_ws, size_t ws_size,
                              hipStream_t stream) {
    (void)in_sizes; (void)n_in; (void)out_size; (void)ws_size;
    const float* x      = (const float*)d_in[0];
    const float* ln1g   = (const float*)d_in[1];
    const float* ln1b   = (const float*)d_in[2];
    const float* qkv_w  = (const float*)d_in[3];
    const float* qkv_b  = (const float*)d_in[4];
    const float* proj_w = (const float*)d_in[5];
    const float* proj_b = (const float*)d_in[6];
    const float* rpb    = (const float*)d_in[7];
    const float* ln2g   = (const float*)d_in[8];
    const float* ln2b   = (const float*)d_in[9];
    const float* fc1_w  = (const float*)d_in[10];
    const float* fc1_b  = (const float*)d_in[11];
    const float* fc2_w  = (const float*)d_in[12];
    const float* fc2_b  = (const float*)d_in[13];
    float* out = (float*)d_out;

    char* ws = (char*)d_ws;
    short* Whead = (short*)(ws + 0);
    short* Wproj = (short*)(ws + 221184);
    short* Wfc1  = (short*)(ws + 294912);
    short* Wfc2  = (short*)(ws + 442368);
    short* battn = (short*)(ws + 589824);

    k_prep<<<256, 256, 0, stream>>>(qkv_w, qkv_b, proj_w, proj_b, fc1_w, fc1_b, fc2_w, rpb,
                                    Whead, Wproj, Wfc1, Wfc2, battn);
    k_fused<<<2048, 768, 0, stream>>>(x, ln1g, ln1b, Whead, Wproj, battn,
                                      ln2g, ln2b, Wfc1, Wfc2, fc2_b, out);
}

// Round 20
// 467.609 us; speedup vs baseline: 1.2796x; 1.2796x over previous
//
#include <hip/hip_runtime.h>
#include <hip/hip_bf16.h>

// Swin block fused: C=180, NH=6, HD=30, WS=8, SS=4, N=64, B=16, H=W=128.
// FINAL = R16/R18 (best measured 467-468us, stable across two runs).
// Ledger: R17 barrier-removal+setprio -6% (L2 weight locality loss);
// R19 A-frag register holds -28% (compiler spilled to scratch);
// R15 conflict-free strides neutral. Structure: 2 windows/block (12 balanced
// waves), y never round-trips HBM, x held in regs, swapped-operand MFMAs,
// per-lane softmax, bias folded into weight col 180.
typedef short s16x8 __attribute__((ext_vector_type(8)));
typedef short s16x4 __attribute__((ext_vector_type(4)));
typedef float f32x4 __attribute__((ext_vector_type(4)));

__device__ __forceinline__ short f2bf(float f) {
    __bf16 h = (__bf16)f;
    return __builtin_bit_cast(short, h);
}
__device__ __forceinline__ float bf2f(short s) {
    return __builtin_bit_cast(float, ((unsigned int)(unsigned short)s) << 16);
}
__device__ __forceinline__ unsigned int pk2(float a, float b) {
    return (unsigned int)(unsigned short)f2bf(a) | ((unsigned int)(unsigned short)f2bf(b) << 16);
}
__device__ __forceinline__ f32x4 mfma16(s16x8 a, s16x8 b, f32x4 c) {
    return __builtin_amdgcn_mfma_f32_16x16x32_bf16(a, b, c, 0, 0, 0);
}
// two ds_read_b64 (8B-aligned rows); conflict-free strides (R15: 10x fewer conflicts)
__device__ __forceinline__ s16x8 ld_b64x2(const short* p) {
    union { s16x8 v; s16x4 h[2]; } u;
    u.h[0] = *(const s16x4*)p;
    u.h[1] = *(const s16x4*)(p + 4);
    return u.v;
}
__device__ __forceinline__ s16x4 pack4(f32x4 a) {
    s16x4 w;
    w[0] = f2bf(a[0]); w[1] = f2bf(a[1]); w[2] = f2bf(a[2]); w[3] = f2bf(a[3]);
    return w;
}

#define SCALE_Q 0.18257418583505536f
#define ONE_BF16 ((short)0x3F80)
// LDS strides in shorts; dword-stride mod 32 has gcd 2 -> ~2-way max on b64 reads.
#define RA 204
#define PS 76
#define HS 196

// ---------------- workspace layout (bytes) ----------------
// Whead bf16 [6][96][192] @ 0       rows: 0-31 q(scaled), 32-63 k, 64-95 v; col180=bias
// Wproj bf16 [192][192]   @ 221184  col180=bias
// Wfc1  bf16 [384][192]   @ 294912  col180=bias
// Wfc2  bf16 [192][384]   @ 442368
// battn bf16 [6][64(n)][64(m)] @ 589824  (n = q-token major)   total 638976

__global__ void k_prep(const float* __restrict__ qkv_w, const float* __restrict__ qkv_b,
                       const float* __restrict__ proj_w, const float* __restrict__ proj_b,
                       const float* __restrict__ fc1_w, const float* __restrict__ fc1_b,
                       const float* __restrict__ fc2_w,
                       const float* __restrict__ rpb,
                       short* __restrict__ Whead, short* __restrict__ Wproj,
                       short* __restrict__ Wfc1, short* __restrict__ Wfc2,
                       short* __restrict__ battn) {
    int gt = blockIdx.x * 256 + threadIdx.x;
    int stride = gridDim.x * 256;
    for (int idx = gt; idx < 6 * 96 * 192; idx += stride) {
        int h = idx / (96 * 192), rem = idx - h * 96 * 192;
        int rr = rem / 192, kk = rem - rr * 192;
        int seg = rr >> 5, hd = rr & 31;
        float val = 0.f;
        if (hd < 30) {
            int ch = seg * 180 + h * 30 + hd;
            if (kk < 180) val = qkv_w[ch * 180 + kk];
            else if (kk == 180) val = qkv_b[ch];
            if (seg == 0) val *= SCALE_Q;
        }
        Whead[idx] = f2bf(val);
    }
    for (int idx = gt; idx < 192 * 192; idx += stride) {
        int rr = idx / 192, kk = idx - rr * 192;
        float val = 0.f;
        if (rr < 180) {
            if (kk < 180) val = proj_w[rr * 180 + kk];
            else if (kk == 180) val = proj_b[rr];
        }
        Wproj[idx] = f2bf(val);
    }
    for (int idx = gt; idx < 384 * 192; idx += stride) {
        int rr = idx / 192, kk = idx - rr * 192;
        float val = 0.f;
        if (rr < 360) {
            if (kk < 180) val = fc1_w[rr * 180 + kk];
            else if (kk == 180) val = fc1_b[rr];
        }
        Wfc1[idx] = f2bf(val);
    }
    for (int idx = gt; idx < 192 * 384; idx += stride) {
        int rr = idx / 384, kk = idx - rr * 384;
        Wfc2[idx] = (rr < 180 && kk < 360) ? f2bf(fc2_w[rr * 360 + kk]) : (short)0;
    }
    // battn[h][n][m] (n = q-token major)
    for (int idx = gt; idx < 6 * 64 * 64; idx += stride) {
        int h = idx >> 12, n = (idx >> 6) & 63, m = idx & 63;
        int r1 = n >> 3, c1 = n & 7, r2 = m >> 3, c2 = m & 7;
        int ridx = (r1 - r2 + 7) * 15 + (c1 - c2 + 7);
        battn[idx] = f2bf(rpb[ridx * 6 + h]);
    }
}

// ---------------- fully fused kernel: TWO windows per block ----------------
// 768 thr = 12 waves = 2 windows x 6 head-waves -> balanced 3 waves/SIMD.
// 1 WG/CU (LDS-capped) => register budget free: x held in f32 regs P1->P4.
// Per-half layout (80384 B; total 160768 <= 163840):
//  regionA @0     (26112): xln[64][RA] -> xout -> ylds -> mo  (pad col180=1.0)
//  regP @26112    (29184): patches 6x4864 (stride PS) -> pout/y bf16 [64][RA]
//  hid  @55296    (25088): bf16 [64][HS] per-K-half fc1 output
__global__ __launch_bounds__(768, 3)
void k_fused(const float* __restrict__ x, const float* __restrict__ g1, const float* __restrict__ b1,
             const short* __restrict__ Whead,
             const short* __restrict__ Wproj,
             const short* __restrict__ battn,
             const float* __restrict__ g2, const float* __restrict__ b2,
             const short* __restrict__ Wfc1,
             const short* __restrict__ Wfc2, const float* __restrict__ fb2,
             float* __restrict__ out) {
    __shared__ __align__(16) char smem[160768];

    const int tid = threadIdx.x;
    const int wvg = tid >> 6;                 // 0..11
    const int half = (wvg >= 6) ? 1 : 0;      // which window
    const int wv = wvg - half * 6;            // local head-wave 0..5
    const int l = tid & 63, l15 = l & 15, lg = l >> 4;
    const int tl = tid - half * 384;          // local tid 0..383

    char* sm = smem + half * 80384;
    short* xln  = (short*)sm;                 // [64][RA]
    short* xout = (short*)sm;                 // overlays
    short* ylds = (short*)sm;                 // overlays
    short* mo   = (short*)sm;                 // overlays (after fc1 reads done)
    short* regP = (short*)(sm + 26112);
    short* pout = regP;                       // bf16 [64][RA] -> becomes y in place
    short* ybuf = regP;
    short* hid  = (short*)(sm + 55296);       // bf16 [64][HS]
    short* patch = regP + wv * 2432;          // 4864 B each

    const int wid = blockIdx.x * 2 + half;
    const int b = wid >> 8, win = wid & 255, wi = win >> 4, wj = win & 15;
    const bool edge = (wi == 15) || (wj == 15);
    const f32x4 vzero = {0.f, 0.f, 0.f, 0.f};

    const int t = tl >> 2, sub = tl & 3;
    size_t rowbase = 0;
    if (tl < 256) {
        const int r = t >> 3, c = t & 7;
        const int gi = (wi * 8 + r + 4) & 127, gj = (wj * 8 + c + 4) & 127;
        rowbase = ((size_t)b * 16384 + (size_t)gi * 128 + gj) * 180;
    }
    const float* xrow = x + rowbase;
    float* yrow = out + rowbase;

    // x held in f32 regs from P1 through P4 (48 VGPRs; budget ~170 at 1 WG/CU)
    float4 xr[12];

    // ---- P1: LN1 -> xln ----
    if (tl < 256) {
        float s1 = 0.f, s2 = 0.f;
#pragma unroll
        for (int m = 0; m < 12; ++m) {
            int jj = sub + 4 * m;
            if (jj < 45) {
                float4 t4 = *(const float4*)&xrow[4 * jj];
                xr[m] = t4;
                s1 += t4.x + t4.y + t4.z + t4.w;
                s2 += t4.x * t4.x + t4.y * t4.y + t4.z * t4.z + t4.w * t4.w;
            }
        }
        s1 += __shfl_xor(s1, 1); s2 += __shfl_xor(s2, 1);
        s1 += __shfl_xor(s1, 2); s2 += __shfl_xor(s2, 2);
        const float mu = s1 * (1.f / 180.f);
        const float rstd = rsqrtf(s2 * (1.f / 180.f) - mu * mu + 1e-5f);
#pragma unroll
        for (int m = 0; m < 12; ++m) {
            int jj = sub + 4 * m;
            if (jj < 45) {
                float4 g4 = *(const float4*)&g1[4 * jj];
                float4 b4 = *(const float4*)&b1[4 * jj];
                s16x4 w;
                w[0] = f2bf((xr[m].x - mu) * rstd * g4.x + b4.x);
                w[1] = f2bf((xr[m].y - mu) * rstd * g4.y + b4.y);
                w[2] = f2bf((xr[m].z - mu) * rstd * g4.z + b4.z);
                w[3] = f2bf((xr[m].w - mu) * rstd * g4.w + b4.w);
                *(s16x4*)&xln[t * RA + 4 * jj] = w;
            }
        }
    } else {
        for (int k = tl - 256; k < 64 * 12; k += 128) {
            int rr = k / 12, cc = k - rr * 12;
            xln[rr * RA + 180 + cc] = (cc == 0) ? ONE_BF16 : (short)0;
        }
    }
    __syncthreads();   // B1: xln ready (both halves)

    // ---- P2: per-wave head staging (bias via col 180), inline A-reads ----
    const short* Wh = Whead + wv * (96 * 192);
    s16x8 qf[4], kf[4], vf[2][2];

    // Q (swapped: D row=ch, col=token) -> patch [64][36]
#pragma unroll
    for (int jl = 0; jl < 2; ++jl) {
        f32x4 acc[4] = {vzero, vzero, vzero, vzero};
#pragma unroll
        for (int ks = 0; ks < 6; ++ks) {
            s16x8 bwk = *(const s16x8*)&Wh[(jl * 16 + l15) * 192 + ks * 32 + lg * 8];
#pragma unroll
            for (int i = 0; i < 4; ++i) {
                s16x8 afi = ld_b64x2(&xln[(i * 16 + l15) * RA + ks * 32 + lg * 8]);
                acc[i] = mfma16(bwk, afi, acc[i]);
            }
        }
#pragma unroll
        for (int i = 0; i < 4; ++i)
            *(s16x4*)&patch[(i * 16 + l15) * 36 + jl * 16 + lg * 4] = pack4(acc[i]);
    }
#pragma unroll
    for (int i = 0; i < 4; ++i) qf[i] = ld_b64x2(&patch[(i * 16 + l15) * 36 + lg * 8]);

    // K (swapped) -> patch [64][36] (reuse)
#pragma unroll
    for (int jl = 0; jl < 2; ++jl) {
        f32x4 acc[4] = {vzero, vzero, vzero, vzero};
#pragma unroll
        for (int ks = 0; ks < 6; ++ks) {
            s16x8 bwk = *(const s16x8*)&Wh[(32 + jl * 16 + l15) * 192 + ks * 32 + lg * 8];
#pragma unroll
            for (int i = 0; i < 4; ++i) {
                s16x8 afi = ld_b64x2(&xln[(i * 16 + l15) * RA + ks * 32 + lg * 8]);
                acc[i] = mfma16(bwk, afi, acc[i]);
            }
        }
#pragma unroll
        for (int i = 0; i < 4; ++i)
            *(s16x4*)&patch[(i * 16 + l15) * 36 + jl * 16 + lg * 4] = pack4(acc[i]);
    }
#pragma unroll
    for (int j = 0; j < 4; ++j) kf[j] = ld_b64x2(&patch[(j * 16 + l15) * 36 + lg * 8]);

    // V (unswapped: D col=hd, rows=token) -> VhT [32][PS]
#pragma unroll
    for (int jl = 0; jl < 2; ++jl) {
        f32x4 acc[4] = {vzero, vzero, vzero, vzero};
#pragma unroll
        for (int ks = 0; ks < 6; ++ks) {
            s16x8 bwk = *(const s16x8*)&Wh[(64 + jl * 16 + l15) * 192 + ks * 32 + lg * 8];
#pragma unroll
            for (int i = 0; i < 4; ++i) {
                s16x8 afi = ld_b64x2(&xln[(i * 16 + l15) * RA + ks * 32 + lg * 8]);
                acc[i] = mfma16(afi, bwk, acc[i]);
            }
        }
#pragma unroll
        for (int i = 0; i < 4; ++i)
            *(s16x4*)&patch[(jl * 16 + l15) * PS + i * 16 + lg * 4] = pack4(acc[i]);
    }
#pragma unroll
    for (int j2 = 0; j2 < 2; ++j2)
#pragma unroll
        for (int ksv = 0; ksv < 2; ++ksv)
            vf[j2][ksv] = ld_b64x2(&patch[(j2 * 16 + l15) * PS + ksv * 32 + lg * 8]);

    __syncthreads();   // Bx: all xln reads done -> region A reusable as xout

    // ---- attention: S^T = mfma(kf,qf); per-lane softmax; PV^T = mfma(vf,pa) ----
    {
        const short* bb = battn + wv * 4096;
#pragma unroll
        for (int i = 0; i < 4; ++i) {
            const int n = i * 16 + l15;            // q-token (lane col)
            f32x4 sc[4];
#pragma unroll
            for (int j = 0; j < 4; ++j) sc[j] = mfma16(kf[j], qf[i], vzero);
            int cnt_n = 0;
            if (edge) {
                int rn = n >> 3, cn = n & 7;
                cnt_n = (wi == 15 ? ((rn >= 4) ? 2 : 1) : 0) * 3 + (wj == 15 ? ((cn >= 4) ? 2 : 1) : 0);
            }
            float p[4][4];
#pragma unroll
            for (int j = 0; j < 4; ++j) {
                s16x4 bv = *(const s16x4*)&bb[n * 64 + j * 16 + lg * 4];
#pragma unroll
                for (int tt = 0; tt < 4; ++tt) {
                    float s = sc[j][tt] + bf2f(bv[tt]);
                    if (edge) {
                        int m = j * 16 + lg * 4 + tt;
                        int rm = m >> 3, cm = m & 7;
                        int cnt_m = (wi == 15 ? ((rm >= 4) ? 2 : 1) : 0) * 3 + (wj == 15 ? ((cm >= 4) ? 2 : 1) : 0);
                        if (cnt_m != cnt_n) s -= 100.f;
                    }
                    p[j][tt] = s;
                }
            }
            float m0 = p[0][0];
#pragma unroll
            for (int j = 0; j < 4; ++j)
#pragma unroll
                for (int tt = 0; tt < 4; ++tt) m0 = fmaxf(m0, p[j][tt]);
            m0 = fmaxf(m0, __shfl_xor(m0, 16));
            m0 = fmaxf(m0, __shfl_xor(m0, 32));
            float s0 = 0.f;
#pragma unroll
            for (int j = 0; j < 4; ++j)
#pragma unroll
                for (int tt = 0; tt < 4; ++tt) { float e = __expf(p[j][tt] - m0); p[j][tt] = e; s0 += e; }
            s0 += __shfl_xor(s0, 16);
            s0 += __shfl_xor(s0, 32);
            const float sm0 = __builtin_amdgcn_rcpf(s0);

            short* pb = patch + (i & 1) * 1216;   // [16][PS] ping-pong
#pragma unroll
            for (int j = 0; j < 4; ++j) {
                f32x4 ps;
#pragma unroll
                for (int tt = 0; tt < 4; ++tt) ps[tt] = p[j][tt] * sm0;
                *(s16x4*)&pb[l15 * PS + j * 16 + lg * 4] = pack4(ps);
            }
            s16x8 pa0 = ld_b64x2(&pb[l15 * PS + lg * 8]);
            s16x8 pa1 = ld_b64x2(&pb[l15 * PS + 32 + lg * 8]);
            f32x4 ov0 = mfma16(vf[0][0], pa0, vzero);   // D: row=hd, col=qtok
            ov0 = mfma16(vf[0][1], pa1, ov0);
            f32x4 ov1 = mfma16(vf[1][0], pa0, vzero);
            ov1 = mfma16(vf[1][1], pa1, ov1);
            short* xo = &xout[n * RA + wv * 30];
            unsigned int w0 = pk2(ov0[0], ov0[1]);
            unsigned int w1 = pk2(ov0[2], ov0[3]);
            *(unsigned int*)&xo[lg * 4] = w0;
            *(unsigned int*)&xo[lg * 4 + 2] = w1;
            unsigned int w2 = pk2(ov1[0], ov1[1]);
            if (lg < 3) {
                unsigned int w3 = pk2(ov1[2], ov1[3]);
                *(unsigned int*)&xo[16 + lg * 4] = w2;
                *(unsigned int*)&xo[16 + lg * 4 + 2] = w3;
            } else {
                *(unsigned int*)&xo[28] = w2;   // hd 28,29
            }
        }
    }
    __syncthreads();   // B3: xout complete, patches dead

    // ---- proj (swapped, inline A-reads) -> pout bf16 [token][ch] ----
#pragma unroll
    for (int jl = 0; jl < 2; ++jl) {
        const int cb = wv * 32 + jl * 16 + lg * 4;
        f32x4 acc[4] = {vzero, vzero, vzero, vzero};
#pragma unroll
        for (int ks = 0; ks < 6; ++ks) {
            s16x8 bwk = *(const s16x8*)&Wproj[(wv * 32 + jl * 16 + l15) * 192 + ks * 32 + lg * 8];
#pragma unroll
            for (int i = 0; i < 4; ++i) {
                s16x8 afi = ld_b64x2(&xout[(i * 16 + l15) * RA + ks * 32 + lg * 8]);
                acc[i] = mfma16(bwk, afi, acc[i]);
            }
        }
        if (cb <= 176) {
#pragma unroll
            for (int i = 0; i < 4; ++i)
                *(s16x4*)&pout[(i * 16 + l15) * RA + cb] = pack4(acc[i]);
        }
    }
    __syncthreads();   // B4: pout ready, xout dead

    // ---- P4: y = x(regs) + pout -> IN PLACE bf16 (ybuf == pout); LN2 -> ylds ----
    if (tl < 256) {
        float s1 = 0.f, s2 = 0.f;
        unsigned int pA[12], pB[12];
#pragma unroll
        for (int m = 0; m < 12; ++m) {
            int jj = sub + 4 * m;
            if (jj < 45) {
                s16x4 pv = *(const s16x4*)&pout[t * RA + 4 * jj];
                float4 y4;
                y4.x = xr[m].x + bf2f(pv[0]); y4.y = xr[m].y + bf2f(pv[1]);
                y4.z = xr[m].z + bf2f(pv[2]); y4.w = xr[m].w + bf2f(pv[3]);
                pA[m] = pk2(y4.x, y4.y);
                pB[m] = pk2(y4.z, y4.w);
                *(unsigned int*)&ybuf[t * RA + 4 * jj] = pA[m];
                *(unsigned int*)&ybuf[t * RA + 4 * jj + 2] = pB[m];
                s1 += y4.x + y4.y + y4.z + y4.w;
                s2 += y4.x * y4.x + y4.y * y4.y + y4.z * y4.z + y4.w * y4.w;
            }
        }
        s1 += __shfl_xor(s1, 1); s2 += __shfl_xor(s2, 1);
        s1 += __shfl_xor(s1, 2); s2 += __shfl_xor(s2, 2);
        const float mu = s1 * (1.f / 180.f);
        const float rstd = rsqrtf(s2 * (1.f / 180.f) - mu * mu + 1e-5f);
#pragma unroll
        for (int m = 0; m < 12; ++m) {
            int jj = sub + 4 * m;
            if (jj < 45) {
                float4 g4 = *(const float4*)&g2[4 * jj];
                float4 b4 = *(const float4*)&b2[4 * jj];
                float ylo0 = bf2f((short)(pA[m] & 0xFFFFu));
                float yhi0 = bf2f((short)(pA[m] >> 16));
                float ylo1 = bf2f((short)(pB[m] & 0xFFFFu));
                float yhi1 = bf2f((short)(pB[m] >> 16));
                s16x4 w;
                w[0] = f2bf((ylo0 - mu) * rstd * g4.x + b4.x);
                w[1] = f2bf((yhi0 - mu) * rstd * g4.y + b4.y);
                w[2] = f2bf((ylo1 - mu) * rstd * g4.z + b4.z);
                w[3] = f2bf((yhi1 - mu) * rstd * g4.w + b4.w);
                *(s16x4*)&ylds[t * RA + 4 * jj] = w;
            }
        }
    } else {
        for (int k = tl - 256; k < 64 * 12; k += 128) {
            int rr = k / 12, cc = k - rr * 12;
            ylds[rr * RA + 180 + cc] = (cc == 0) ? ONE_BF16 : (short)0;
        }
    }
    __syncthreads();   // B5: ylds + y(bf16, in place) ready

    // ---- MLP in 2 K-halves of 192: fc1 (2 tiles/wave) -> hid [64][HS] -> fc2 ----
    f32x4 acc3[2][4];
#pragma unroll
    for (int jl = 0; jl < 2; ++jl)
#pragma unroll
        for (int i = 0; i < 4; ++i) acc3[jl][i] = vzero;

#pragma unroll
    for (int kh = 0; kh < 2; ++kh) {
        // fc1: wave's out tiles j = kh*12 + wv*2 + jl; GELU; packed store
#pragma unroll
        for (int jl = 0; jl < 2; ++jl) {
            f32x4 acc[4] = {vzero, vzero, vzero, vzero};
#pragma unroll
            for (int ks = 0; ks < 6; ++ks) {
                s16x8 bwk = *(const s16x8*)&Wfc1[((kh * 12 + wv * 2 + jl) * 16 + l15) * 192 + ks * 32 + lg * 8];
#pragma unroll
                for (int i = 0; i < 4; ++i) {
                    s16x8 ai = ld_b64x2(&ylds[(i * 16 + l15) * RA + ks * 32 + lg * 8]);
                    acc[i] = mfma16(bwk, ai, acc[i]);
                }
            }
            const int clb = (wv * 2 + jl) * 16 + lg * 4;   // half-local channel base
#pragma unroll
            for (int i = 0; i < 4; ++i) {
                s16x4 w;
#pragma unroll
                for (int tt = 0; tt < 4; ++tt) {
                    float v = acc[i][tt];
                    float u = v * (1.f + 0.044715f * v * v);
                    float e = __expf(-1.5957691216f * u);
                    w[tt] = f2bf(v * __builtin_amdgcn_rcpf(1.f + e));
                }
                *(s16x4*)&hid[(i * 16 + l15) * HS + clb] = w;
            }
        }
        __syncthreads();   // hid(kh) ready
        // fc2 partial: K = cols [kh*192, kh*192+192) of Wfc2
#pragma unroll
        for (int ks = 0; ks < 6; ++ks) {
            s16x8 a[4];
#pragma unroll
            for (int i = 0; i < 4; ++i)
                a[i] = ld_b64x2(&hid[(i * 16 + l15) * HS + ks * 32 + lg * 8]);
#pragma unroll
            for (int jl = 0; jl < 2; ++jl) {
                s16x8 bw2 = *(const s16x8*)&Wfc2[((wv * 2 + jl) * 16 + l15) * 384 + kh * 192 + ks * 32 + lg * 8];
#pragma unroll
                for (int i = 0; i < 4; ++i) acc3[jl][i] = mfma16(bw2, a[i], acc3[jl][i]);
            }
        }
        __syncthreads();   // hid consumed (next kh overwrites)
    }

    // ---- fc2 out + fb2 -> mo bf16 [token][ch] (regionA; ylds dead) ----
#pragma unroll
    for (int jl = 0; jl < 2; ++jl) {
        const int cb = (wv * 2 + jl) * 16 + lg * 4;
        if (cb <= 176) {
            float4 f4 = *(const float4*)&fb2[cb];
#pragma unroll
            for (int i = 0; i < 4; ++i) {
                f32x4 a2;
                a2[0] = acc3[jl][i][0] + f4.x;
                a2[1] = acc3[jl][i][1] + f4.y;
                a2[2] = acc3[jl][i][2] + f4.z;
                a2[3] = acc3[jl][i][3] + f4.w;
                *(s16x4*)&mo[(i * 16 + l15) * RA + cb] = pack4(a2);
            }
        }
    }
    __syncthreads();   // B7: mo ready

    // ---- final: out = y(bf16 LDS) + mo, single coalesced write pass ----
    if (tl < 256) {
#pragma unroll
        for (int m = 0; m < 12; ++m) {
            int jj = sub + 4 * m;
            if (jj < 45) {
                s16x4 yv4 = *(const s16x4*)&ybuf[t * RA + 4 * jj];
                s16x4 mv = *(const s16x4*)&mo[t * RA + 4 * jj];
                float4 o;
                o.x = bf2f(yv4[0]) + bf2f(mv[0]);
                o.y = bf2f(yv4[1]) + bf2f(mv[1]);
                o.z = bf2f(yv4[2]) + bf2f(mv[2]);
                o.w = bf2f(yv4[3]) + bf2f(mv[3]);
                *(float4*)&yrow[4 * jj] = o;
            }
        }
    }
}

extern "C" void kernel_launch(void* const* d_in, const int* in_sizes, int n_in,
                              void* d_out, int out_size, void* d_ws, size_t ws_size,
                              hipStream_t stream) {
    (void)in_sizes; (void)n_in; (void)out_size; (void)ws_size;
    const float* x      = (const float*)d_in[0];
    const float* ln1g   = (const float*)d_in[1];
    const float* ln1b   = (const float*)d_in[2];
    const float* qkv_w  = (const float*)d_in[3];
    const float* qkv_b  = (const float*)d_in[4];
    const float* proj_w = (const float*)d_in[5];
    const float* proj_b = (const float*)d_in[6];
    const float* rpb    = (const float*)d_in[7];
    const float* ln2g   = (const float*)d_in[8];
    const float* ln2b   = (const float*)d_in[9];
    const float* fc1_w  = (const float*)d_in[10];
    const float* fc1_b  = (const float*)d_in[11];
    const float* fc2_w  = (const float*)d_in[12];
    const float* fc2_b  = (const float*)d_in[13];
    float* out = (float*)d_out;

    char* ws = (char*)d_ws;
    short* Whead = (short*)(ws + 0);
    short* Wproj = (short*)(ws + 221184);
    short* Wfc1  = (short*)(ws + 294912);
    short* Wfc2  = (short*)(ws + 442368);
    short* battn = (short*)(ws + 589824);

    k_prep<<<256, 256, 0, stream>>>(qkv_w, qkv_b, proj_w, proj_b, fc1_w, fc1_b, fc2_w, rpb,
                                    Whead, Wproj, Wfc1, Wfc2, battn);
    k_fused<<<2048, 768, 0, stream>>>(x, ln1g, ln1b, Whead, Wproj, battn,
                                      ln2g, ln2b, Wfc1, Wfc2, fc2_b, out);
}